// Round 2
// baseline (334.484 us; speedup 1.0000x reference)
//
#include <hip/hip_runtime.h>

// HardBinaryVote: in[31][2000000] int32 in {0,1}; out[b] = (sum_v in[v][b] >= 16)
// 31 voters (odd) -> no ties -> majority == (count of ones >= 16), out is int32.
// Memory-bound: 248 MB read + 8 MB write -> HBM floor ~41 us.
// Each thread owns TWO adjacent int4 columns: the second load folds into the
// 13-bit signed immediate offset (base+16), halving address-calc per byte and
// doubling per-wave MLP (2 x 1KB wave-requests in flight per unrolled row).

constexpr int NV = 31;            // voters
constexpr int BATCH = 2000000;    // batch columns
constexpr int NVEC = BATCH / 4;   // int4 elements per row (500000)
constexpr int NPAIR = NVEC / 2;   // int4-pairs per row (250000)

__global__ __launch_bounds__(256) void vote_kernel(const int* __restrict__ in,
                                                   int* __restrict__ out) {
    const int pair = blockIdx.x * blockDim.x + threadIdx.x;
    if (pair >= NPAIR) return;

    const int4* p = reinterpret_cast<const int4*>(in) + (size_t)pair * 2;
    int a0 = 0, a1 = 0, a2 = 0, a3 = 0;
    int b0 = 0, b1 = 0, b2 = 0, b3 = 0;
#pragma unroll
    for (int v = 0; v < NV; ++v) {
        int4 x = p[(size_t)v * NVEC];      // coalesced 16B
        int4 y = p[(size_t)v * NVEC + 1];  // same base, imm offset +16
        a0 += x.x; a1 += x.y; a2 += x.z; a3 += x.w;
        b0 += y.x; b1 += y.y; b2 += y.z; b3 += y.w;
    }
    int4 r0, r1;
    r0.x = (a0 >= 16) ? 1 : 0;
    r0.y = (a1 >= 16) ? 1 : 0;
    r0.z = (a2 >= 16) ? 1 : 0;
    r0.w = (a3 >= 16) ? 1 : 0;
    r1.x = (b0 >= 16) ? 1 : 0;
    r1.y = (b1 >= 16) ? 1 : 0;
    r1.z = (b2 >= 16) ? 1 : 0;
    r1.w = (b3 >= 16) ? 1 : 0;

    int4* o = reinterpret_cast<int4*>(out) + (size_t)pair * 2;
    o[0] = r0;
    o[1] = r1;
}

extern "C" void kernel_launch(void* const* d_in, const int* in_sizes, int n_in,
                              void* d_out, int out_size, void* d_ws, size_t ws_size,
                              hipStream_t stream) {
    const int* in = reinterpret_cast<const int*>(d_in[0]);
    int* out = reinterpret_cast<int*>(d_out);

    const int threads = 256;
    const int blocks = (NPAIR + threads - 1) / threads;  // 977
    vote_kernel<<<blocks, threads, 0, stream>>>(in, out);
}